// Round 5
// baseline (195.705 us; speedup 1.0000x reference)
//
#include <hip/hip_runtime.h>
#include <hip/hip_bf16.h>
#include <cstdint>
#include <cstddef>

typedef __bf16 y8 __attribute__((ext_vector_type(8)));
typedef float f4 __attribute__((ext_vector_type(4)));
typedef unsigned short u16t;

#define NB 4
#define TT 2048
#define DD 1024
#define HH 16

static constexpr size_t OUT0 = (size_t)NB * TT * DD;  // 8388608 floats (out), then present
#define QSCALE 0.180336880111120426f                  // 0.125 * log2(e): softmax in exp2 domain

__device__ __forceinline__ u16t bf16r(float f) {
    union { float f; unsigned u; } x; x.f = f;
    return (u16t)((x.u + 0x7FFFu + ((x.u >> 16) & 1u)) >> 16);
}

__device__ __forceinline__ unsigned cvtpk(float lo, float hi) {
    unsigned r;
    asm("v_cvt_pk_bf16_f32 %0, %1, %2" : "=v"(r) : "v"(lo), "v"(hi));
    return r;
}

#define GLDS16(g, s) __builtin_amdgcn_global_load_lds( \
    (__attribute__((address_space(1))) void*)(g),      \
    (__attribute__((address_space(3))) void*)(s), 16, 0, 0)

#define BARX() asm volatile("s_barrier" ::: "memory")
#define VMW(n) asm volatile("s_waitcnt vmcnt(" #n ")" ::: "memory")
#define LGKM0() asm volatile("s_waitcnt lgkmcnt(0)" ::: "memory")

// ---------------------------------------------------------------- conversions
__global__ __launch_bounds__(256)
void cvt_f32_bf16(const float* __restrict__ in, u16t* __restrict__ outp, int n) {
    int i = (blockIdx.x * 256 + threadIdx.x) * 8;
    if (i >= n) return;
    float4 a = *(const float4*)(in + i);
    float4 b = *(const float4*)(in + i + 4);
    union { u16t h[8]; uint4 q; } u;
    u.h[0] = bf16r(a.x); u.h[1] = bf16r(a.y); u.h[2] = bf16r(a.z); u.h[3] = bf16r(a.w);
    u.h[4] = bf16r(b.x); u.h[5] = bf16r(b.y); u.h[6] = bf16r(b.z); u.h[7] = bf16r(b.w);
    *(uint4*)(outp + i) = u.q;
}

// in: (Kd, Nd) f32 row-major -> out: (Nd, Kd) bf16 row-major
__global__ __launch_bounds__(256)
void transpose_w(const float* __restrict__ in, u16t* __restrict__ outp, int Kd, int Nd) {
    __shared__ float tile[32][33];
    const int n0 = blockIdx.x * 32, k0 = blockIdx.y * 32;
    const int tx = threadIdx.x & 31, ty = threadIdx.x >> 5;
    for (int yy = ty; yy < 32; yy += 8)
        tile[yy][tx] = in[(size_t)(k0 + yy) * Nd + n0 + tx];
    __syncthreads();
    for (int yy = ty; yy < 32; yy += 8)
        outp[(size_t)(n0 + yy) * Kd + k0 + tx] = bf16r(tile[tx][yy]);
}

// ---------------------------------------------------------------- QKV GEMM, 256^2 8-phase
// C(8192,3072) = A(8192,1024)bf16 * Bt(3072,1024)bf16^T + bias, fused qkv epilogue.
// 8 waves (2M x 4N), BK=64, 2 K-tiles/iter, 8 phases/iter. Staging protocol:
//   dbuf = tile&1. Per K-tile (4 phases): reads issue A-halves at p0/p2, B-halves p0/p1.
//   Dead windows: B-halves from p2, A-halves from p4 (wave-quadrant order Q00,Q01,Q10,Q11).
//   Stage slots (group g reads dbuf g, tile t0+g):
//     p0: A(t0+1+g, h0)  p1: A(t0+1+g, h1)  p2: B(t0+2+g, h0)  p3: B(t0+2+g, h1)
//   vmcnt(4) at p3 of each group enforces the next-consumed tile complete while
//   keeping the newest 2 stages (4 loads) in flight. Last iteration drains (vmcnt 0).
__global__ __launch_bounds__(512, 1)
void qkv_gemm_8ph(const u16t* __restrict__ A, const u16t* __restrict__ Bt,
                  const float* __restrict__ bias, float* __restrict__ pres,
                  u16t* __restrict__ qb, u16t* __restrict__ kb, u16t* __restrict__ vtb)
{
    constexpr int K = DD;        // 1024
    constexpr int NT = K / 64;   // 16 K-tiles
    __shared__ u16t ldsA[2][256 * 64];   // 2 x 32 KB
    __shared__ u16t ldsB[2][256 * 64];   // 2 x 32 KB
    const int tid = threadIdx.x;
    const int w = tid >> 6, l = tid & 63;
    const int wm = w >> 2, wn = w & 3;
    const int lr = l & 15, lq = l >> 4;
    const int bm = blockIdx.x * 256;
    const int bn = blockIdx.y * 256;

    auto stageA = [&](int t, int h) {   // one 128-row half of A's K-tile t: 2 GLDS/thread
        if (t >= NT) return;
        const int d = t & 1;
#pragma unroll
        for (int c = 0; c < 2; ++c) {
            const int L = tid * 16 + (c << 13);
            const int row = L >> 7;                               // 0..127 within half
            const int col = (((L >> 4) & 7) ^ (row & 7)) << 3;    // inverse-swizzled source
            GLDS16(A + (size_t)(bm + h * 128 + row) * K + t * 64 + col,
                   (char*)ldsA[d] + (h << 14) + (c << 13) + (w << 10));
        }
    };
    auto stageB = [&](int t, int h) {
        if (t >= NT) return;
        const int d = t & 1;
#pragma unroll
        for (int c = 0; c < 2; ++c) {
            const int L = tid * 16 + (c << 13);
            const int row = L >> 7;
            const int col = (((L >> 4) & 7) ^ (row & 7)) << 3;
            GLDS16(Bt + (size_t)(bn + h * 128 + row) * K + t * 64 + col,
                   (char*)ldsB[d] + (h << 14) + (c << 13) + (w << 10));
        }
    };

    y8 af[4][2];        // current qm's A-frags
    y8 bf[2][2][2];     // [qn][n][ks] B-frags, both qn kept live
    f4 acc[8][4] = {};

    auto ldAf = [&](int d, int qm) {
#pragma unroll
        for (int ks = 0; ks < 2; ++ks)
#pragma unroll
            for (int m = 0; m < 4; ++m) {
                const int row = wm * 128 + qm * 64 + m * 16 + lr;
                const int slot = (lq + ks * 4) ^ (row & 7);
                af[m][ks] = *(const y8*)((const char*)ldsA[d] + row * 128 + (slot << 4));
            }
    };
    auto ldBf = [&](int d, int qn) {
#pragma unroll
        for (int ks = 0; ks < 2; ++ks)
#pragma unroll
            for (int n = 0; n < 2; ++n) {
                const int row = wn * 64 + qn * 32 + n * 16 + lr;
                const int slot = (lq + ks * 4) ^ (row & 7);
                bf[qn][n][ks] = *(const y8*)((const char*)ldsB[d] + row * 128 + (slot << 4));
            }
    };
    auto mfmaQ = [&](int qm, int qn) {
        __builtin_amdgcn_s_setprio(1);
#pragma unroll
        for (int ks = 0; ks < 2; ++ks)
#pragma unroll
            for (int m = 0; m < 4; ++m)
#pragma unroll
                for (int n = 0; n < 2; ++n)
                    acc[qm * 4 + m][qn * 2 + n] = __builtin_amdgcn_mfma_f32_16x16x32_bf16(
                        af[m][ks], bf[qn][n][ks], acc[qm * 4 + m][qn * 2 + n], 0, 0, 0);
        __builtin_amdgcn_s_setprio(0);
    };

    // prologue: tile0 fully + tile1 B-halves; leave tile1-B (4 loads) in flight
    stageA(0, 0); stageA(0, 1); stageB(0, 0); stageB(0, 1);
    stageB(1, 0); stageB(1, 1);
    VMW(4);
    BARX();

    for (int it = 0; it < NT / 2; ++it) {
        const int t0 = 2 * it;
        const bool last = (it == NT / 2 - 1);
#pragma unroll
        for (int g = 0; g < 2; ++g) {
            // p0: A(qm=0) + B(qn=0) frags; stage next A-half0
            ldAf(g, 0); ldBf(g, 0);
            stageA(t0 + 1 + g, 0);
            BARX(); LGKM0(); mfmaQ(0, 0); BARX();
            // p1: B(qn=1) frags; stage next A-half1
            ldBf(g, 1);
            stageA(t0 + 1 + g, 1);
            BARX(); LGKM0(); mfmaQ(0, 1); BARX();
            // p2: A(qm=1) frags; stage B-half0 (B of this dbuf is dead now)
            ldAf(g, 1);
            stageB(t0 + 2 + g, 0);
            BARX(); LGKM0(); mfmaQ(1, 0); BARX();
            // p3: stage B-half1; counted vmcnt (drain only in last iteration)
            stageB(t0 + 2 + g, 1);
            if (last) { VMW(0); } else { VMW(4); }
            BARX(); mfmaQ(1, 1); BARX();
        }
    }

    // epilogue: q scaled (softmax fold), k + present, v transposed + present
    const int part = bn >> 10;  // 0=q, 1=k, 2=v (256-col tile never crosses 1024 boundary)
#pragma unroll
    for (int mf = 0; mf < 8; ++mf) {
        const int rowb = bm + wm * 128 + mf * 16 + 4 * lq;
        const int b0 = rowb >> 11, tr0 = rowb & 2047;  // 4 rows never cross batch
#pragma unroll
        for (int nf = 0; nf < 4; ++nf) {
            const int colg = bn + wn * 64 + nf * 16 + lr;
            const float bv = bias[colg];
            const int cl = colg & 1023;
            const int h = cl >> 6, d = cl & 63;
            float vals[4];
#pragma unroll
            for (int r = 0; r < 4; ++r) vals[r] = acc[mf][nf][r] + bv;
            if (part == 0) {
#pragma unroll
                for (int r = 0; r < 4; ++r)
                    qb[(((size_t)(b0 * HH + h)) * TT + tr0 + r) * 64 + d] =
                        bf16r(vals[r] * QSCALE);
            } else if (part == 1) {
#pragma unroll
                for (int r = 0; r < 4; ++r) {
                    kb[(((size_t)(b0 * HH + h)) * TT + tr0 + r) * 64 + d] = bf16r(vals[r]);
                    pres[OUT0 + (((size_t)((b0 * 2 + 0) * HH + h)) * TT + tr0 + r) * 64 + d] = vals[r];
                }
            } else {
#pragma unroll
                for (int r = 0; r < 4; ++r)
                    pres[OUT0 + (((size_t)((b0 * 2 + 1) * HH + h)) * TT + tr0 + r) * 64 + d] = vals[r];
                uint2 pk;
                pk.x = cvtpk(vals[0], vals[1]);
                pk.y = cvtpk(vals[2], vals[3]);
                *(uint2*)(vtb + ((size_t)(b0 * HH + h) * 64 + d) * TT + tr0) = pk;
            }
        }
    }
}

// ---------------------------------------------------------------- proj GEMM (128^2, 2-phase)
__global__ __launch_bounds__(256, 2)
void gemm_proj(const u16t* __restrict__ A, const u16t* __restrict__ Bt,
               const float* __restrict__ bias, float* __restrict__ C,
               int M, int N, int K)
{
    __shared__ u16t ldsA[2][128 * 64];
    __shared__ u16t ldsB[2][128 * 64];
    const int tid = threadIdx.x;
    const int w = tid >> 6, l = tid & 63;
    const int wr = w >> 1, wc = w & 1;
    const int lr = l & 15, lq = l >> 4;
    const int bm = blockIdx.x * 128;
    const int bn = blockIdx.y * 128;

    auto stage = [&](int k0, int pi) {
#pragma unroll
        for (int c = 0; c < 4; ++c) {
            const int L = ((w * 64 + l) << 4) + (c << 12);
            const int row = L >> 7;
            const int col = (((L >> 4) & 7) ^ (row & 7)) << 3;
            GLDS16(A + (size_t)(bm + row) * K + k0 + col,
                   (char*)ldsA[pi] + (w << 10) + (c << 12));
            GLDS16(Bt + (size_t)(bn + row) * K + k0 + col,
                   (char*)ldsB[pi] + (w << 10) + (c << 12));
        }
    };

    f4 acc[4][4] = {};

    stage(0, 0);
    __syncthreads();
    int cur = 0;
    const int nt = K >> 6;
    for (int t = 0; t < nt; ++t) {
        if (t + 1 < nt) stage((t + 1) << 6, cur ^ 1);
        const char* La = (const char*)ldsA[cur];
        const char* Lb = (const char*)ldsB[cur];
#pragma unroll
        for (int ks = 0; ks < 2; ++ks) {
            y8 af[4], bfv[4];
#pragma unroll
            for (int m = 0; m < 4; ++m) {
                const int row = wr * 64 + m * 16 + lr;
                const int slot = (lq + ks * 4) ^ (row & 7);
                af[m] = *(const y8*)(La + row * 128 + (slot << 4));
            }
#pragma unroll
            for (int n = 0; n < 4; ++n) {
                const int row = wc * 64 + n * 16 + lr;
                const int slot = (lq + ks * 4) ^ (row & 7);
                bfv[n] = *(const y8*)(Lb + row * 128 + (slot << 4));
            }
#pragma unroll
            for (int m = 0; m < 4; ++m)
#pragma unroll
                for (int n = 0; n < 4; ++n)
                    acc[m][n] = __builtin_amdgcn_mfma_f32_16x16x32_bf16(af[m], bfv[n], acc[m][n], 0, 0, 0);
        }
        __syncthreads();
        cur ^= 1;
    }

#pragma unroll
    for (int m = 0; m < 4; ++m) {
        const int rowb = bm + wr * 64 + m * 16 + 4 * lq;
#pragma unroll
        for (int n = 0; n < 4; ++n) {
            const int col = bn + wc * 64 + n * 16 + lr;
            const float bv = bias[col];
#pragma unroll
            for (int r = 0; r < 4; ++r)
                C[(size_t)(rowb + r) * N + col] = acc[m][n][r] + bv;
        }
    }
}

// ---------------------------------------------------------------- attention
// Block = (qt, bh): 128 q-rows, 4 waves x 32 rows. KV tile 64, double-buffered.
// SWAPPED operands: S = mfma(K,Q) so softmax state is per-lane (query = lane&15);
// O = mfma(V,P) keeps query = lane&15. Softmax in exp2 domain (scale folded into Q).
// T13 defer-max (THR=8). P routed via per-wave swizzled LDS (b64 packed writes).
__global__ __launch_bounds__(256, 2)
void attn_fwd(const u16t* __restrict__ qg, const u16t* __restrict__ kg,
              const u16t* __restrict__ vtg, u16t* __restrict__ og)
{
    __shared__ u16t sQ[128 * 64];      // 16 KB
    __shared__ u16t sK[2 * 64 * 64];   // 16 KB (double buffer)
    __shared__ u16t sV[2 * 64 * 64];   // 16 KB
    __shared__ u16t sP[4 * 32 * 64];   // 16 KB (per-wave 32x64)
    const int tid = threadIdx.x;
    const int w = tid >> 6, l = tid & 63;
    const int lr = l & 15, lq = l >> 4;
    const int qt = 15 - blockIdx.y;    // long blocks first
    const int bh = blockIdx.x;
    const int b = bh >> 4, h = bh & 15;
    const u16t* qsrc = qg + (size_t)bh * TT * 64;
    const u16t* ksrc = kg + (size_t)bh * TT * 64;
    const u16t* vsrc = vtg + (size_t)bh * 64 * TT;

    auto stageKV = [&](int kt, int pi) {
        const int kv0 = kt << 6;
#pragma unroll
        for (int c = 0; c < 2; ++c) {
            const int L = ((w * 64 + l) << 4) + (c << 12);
            const int row = L >> 7;
            const int col = (((L >> 4) & 7) ^ (row & 7)) << 3;
            GLDS16(ksrc + (kv0 + row) * 64 + col,
                   (char*)sK + (pi << 13) + (w << 10) + (c << 12));
            GLDS16(vsrc + (size_t)row * TT + kv0 + col,
                   (char*)sV + (pi << 13) + (w << 10) + (c << 12));
        }
    };

    // stage Q tile (128 x 64) + KV tile 0
#pragma unroll
    for (int c = 0; c < 4; ++c) {
        const int L = ((w * 64 + l) << 4) + (c << 12);
        const int row = L >> 7;
        const int col = (((L >> 4) & 7) ^ (row & 7)) << 3;
        GLDS16(qsrc + (qt * 128 + row) * 64 + col, (char*)sQ + (w << 10) + (c << 12));
    }
    stageKV(0, 0);
    __syncthreads();

    y8 qf[2][2];
#pragma unroll
    for (int qm = 0; qm < 2; ++qm)
#pragma unroll
        for (int ks = 0; ks < 2; ++ks) {
            const int row = w * 32 + qm * 16 + lr;
            const int slot = (lq + ks * 4) ^ (row & 7);
            qf[qm][ks] = *(const y8*)((const char*)sQ + row * 128 + (slot << 4));
        }

    f4 o[2][4] = {};
    float mrow[2] = {-1e30f, -1e30f};
    float lsum[2] = {0.f, 0.f};

    char* Pw = (char*)sP + (w << 12);  // per-wave 32x64 bf16 region
    const int qmax = qt * 128 + w * 32 + 31;  // wave's last q-row
    const int ktiles = 2 * qt + 2;
    int cur = 0;

    for (int kt = 0; kt < ktiles; ++kt) {
        __syncthreads();  // buf[cur] staged; all waves done reading buf[cur^1]
        if (kt + 1 < ktiles) stageKV(kt + 1, cur ^ 1);
        const int kv0 = kt << 6;
        if (kv0 <= qmax) {  // tile not fully masked for this wave
            const char* Kb = (const char*)sK + (cur << 13);
            const char* Vb = (const char*)sV + (cur << 13);

            // S^T tiles: s[qm][n] = mfma(K,Q): lane holds S[key n*16+4lq+r][query lane&15]
            f4 s[2][4] = {};
            __builtin_amdgcn_s_setprio(1);
#pragma unroll
            for (int ks = 0; ks < 2; ++ks) {
                y8 kf[4];
#pragma unroll
                for (int n = 0; n < 4; ++n) {
                    const int row = n * 16 + lr;
                    const int slot = (lq + ks * 4) ^ (row & 7);
                    kf[n] = *(const y8*)(Kb + row * 128 + (slot << 4));
                }
#pragma unroll
                for (int qm = 0; qm < 2; ++qm)
#pragma unroll
                    for (int n = 0; n < 4; ++n)
                        s[qm][n] = __builtin_amdgcn_mfma_f32_16x16x32_bf16(kf[n], qf[qm][ks], s[qm][n], 0, 0, 0);
            }
            __builtin_amdgcn_s_setprio(0);

#pragma unroll
            for (int qm = 0; qm < 2; ++qm) {
                const int qb0 = qt * 128 + w * 32 + qm * 16;
                if (kv0 + 63 > qb0) {  // tile crosses diagonal for this m-tile
                    const int query = qb0 + lr;
#pragma unroll
                    for (int n = 0; n < 4; ++n)
#pragma unroll
                        for (int r = 0; r < 4; ++r)
                            if (kv0 + n * 16 + 4 * lq + r > query) s[qm][n][r] = -1e30f;
                }

                // per-lane row max (query = lane&15): in-lane tree + 2 shfls
                float mx = -1e30f;
#pragma unroll
                for (int n = 0; n < 4; ++n)
                    mx = fmaxf(mx, fmaxf(fmaxf(s[qm][n][0], s[qm][n][1]),
                                         fmaxf(s[qm][n][2], s[qm][n][3])));
                mx = fmaxf(mx, __shfl_xor(mx, 16));
                mx = fmaxf(mx, __shfl_xor(mx, 32));

                // T13 defer-max: rescale only when max grows past THR=8 (exp2 domain)
                if (!__all(mx <= mrow[qm] + 8.f)) {
                    const float newm = fmaxf(mrow[qm], mx);
                    const float corr = exp2f(mrow[qm] - newm);
                    mrow[qm] = newm;
                    lsum[qm] *= corr;
#pragma unroll
                    for (int n = 0; n < 4; ++n) o[qm][n] *= corr;
                }

                float rs = 0.f;
#pragma unroll
                for (int n = 0; n < 4; ++n)
#pragma unroll
                    for (int r = 0; r < 4; ++r) {
                        const float p = exp2f(s[qm][n][r] - mrow[qm]);
                        s[qm][n][r] = p;
                        rs += p;
                    }
                lsum[qm] += rs;

                // P -> per-wave LDS: keys contiguous over r -> packed b64 writes
                const int prow = qm * 16 + lr;
                const int rbase = prow * 128 + ((lq & 1) << 3);
#pragma unroll
                for (int n = 0; n < 4; ++n) {
                    uint2 pk;
                    pk.x = cvtpk(s[qm][n][0], s[qm][n][1]);
                    pk.y = cvtpk(s[qm][n][2], s[qm][n][3]);
                    const int sIdx = 2 * n + (lq >> 1);
                    *(uint2*)(Pw + rbase + ((sIdx ^ (prow & 7)) << 4)) = pk;
                }
            }

            // O += V^T x P (swapped): lane holds O[d=n*16+4lq+r][query lane&15]
            __builtin_amdgcn_s_setprio(1);
#pragma unroll
            for (int ks = 0; ks < 2; ++ks) {
                y8 vf[4], pf[2];
#pragma unroll
                for (int n = 0; n < 4; ++n) {
                    const int row = n * 16 + lr;
                    const int slot = (lq + ks * 4) ^ (row & 7);
                    vf[n] = *(const y8*)(Vb + row * 128 + (slot << 4));
                }
#pragma unroll
                for (int qm = 0; qm < 2; ++qm) {
                    const int row = qm * 16 + lr;
                    const int slot = (lq + ks * 4) ^ (row & 7);
                    pf[qm] = *(const y8*)(Pw + row * 128 + (slot << 4));
                }
#pragma unroll
                for (int qm = 0; qm < 2; ++qm)
#pragma unroll
                    for (int n = 0; n < 4; ++n)
                        o[qm][n] = __builtin_amdgcn_mfma_f32_16x16x32_bf16(vf[n], pf[qm], o[qm][n], 0, 0, 0);
            }
            __builtin_amdgcn_s_setprio(0);
        }
        cur ^= 1;
    }

    // epilogue: lsum reduce (2 shfls), normalize, packed bf16 store
#pragma unroll
    for (int qm = 0; qm < 2; ++qm) {
        float t = lsum[qm];
        t += __shfl_xor(t, 16);
        t += __shfl_xor(t, 32);
        const float inv = 1.0f / t;
        const int trow = qt * 128 + w * 32 + qm * 16 + lr;
#pragma unroll
        for (int n = 0; n < 4; ++n) {
            uint2 pk;
            pk.x = cvtpk(o[qm][n][0] * inv, o[qm][n][1] * inv);
            pk.y = cvtpk(o[qm][n][2] * inv, o[qm][n][3] * inv);
            *(uint2*)(og + ((size_t)(b * TT + trow)) * DD + h * 64 + n * 16 + 4 * lq) = pk;
        }
    }
}

// ---------------------------------------------------------------- launch
extern "C" void kernel_launch(void* const* d_in, const int* in_sizes, int n_in,
                              void* d_out, int out_size, void* d_ws, size_t ws_size,
                              hipStream_t stream) {
    const float* x      = (const float*)d_in[0];
    const float* w_attn = (const float*)d_in[1];
    const float* b_attn = (const float*)d_in[2];
    const float* w_proj = (const float*)d_in[3];
    const float* b_proj = (const float*)d_in[4];
    float* outp = (float*)d_out;
    char* ws = (char*)d_ws;

    // workspace layout (bytes)
    u16t* xb  = (u16t*)(ws + 0);          // 8192x1024 bf16 (x, later reused as attn_out)
    u16t* wta = (u16t*)(ws + 16777216);   // 3072x1024 bf16 (w_attn^T)
    u16t* wtp = (u16t*)(ws + 23068672);   // 1024x1024 bf16 (w_proj^T)
    u16t* qb  = (u16t*)(ws + 25165824);   // (B,H,T,64) bf16, pre-scaled by QSCALE
    u16t* kb  = (u16t*)(ws + 41943040);   // (B,H,T,64) bf16
    u16t* vtb = (u16t*)(ws + 58720256);   // (B,H,64,T) bf16 (written transposed by GEMM)
    if (ws_size < 75497472) return;       // loud failure rather than OOB writes

    cvt_f32_bf16<<<4096, 256, 0, stream>>>(x, xb, 8388608);
    transpose_w<<<dim3(96, 32), 256, 0, stream>>>(w_attn, wta, 1024, 3072);
    transpose_w<<<dim3(32, 32), 256, 0, stream>>>(w_proj, wtp, 1024, 1024);

    qkv_gemm_8ph<<<dim3(32, 12), 512, 0, stream>>>(xb, wta, b_attn, outp, qb, kb, vtb);
    attn_fwd<<<dim3(64, 16), 256, 0, stream>>>(qb, kb, vtb, xb /* reuse as attn_out */);
    gemm_proj<<<dim3(64, 8), 256, 0, stream>>>(xb, wtp, b_proj, outp, 8192, 1024, 1024);
}

// Round 6
// 193.998 us; speedup vs baseline: 1.0088x; 1.0088x over previous
//
#include <hip/hip_runtime.h>
#include <hip/hip_bf16.h>
#include <cstdint>
#include <cstddef>

typedef __bf16 y8 __attribute__((ext_vector_type(8)));
typedef float f4 __attribute__((ext_vector_type(4)));
typedef unsigned short u16t;

#define NB 4
#define TT 2048
#define DD 1024
#define HH 16

static constexpr size_t OUT0 = (size_t)NB * TT * DD;  // 8388608 floats (out), then present
#define QSCALE 0.180336880111120426f                  // 0.125 * log2(e): softmax in exp2 domain

__device__ __forceinline__ u16t bf16r(float f) {
    union { float f; unsigned u; } x; x.f = f;
    return (u16t)((x.u + 0x7FFFu + ((x.u >> 16) & 1u)) >> 16);
}

__device__ __forceinline__ unsigned cvtpk(float lo, float hi) {
    unsigned r;
    asm("v_cvt_pk_bf16_f32 %0, %1, %2" : "=v"(r) : "v"(lo), "v"(hi));
    return r;
}

#define GLDS16(g, s) __builtin_amdgcn_global_load_lds( \
    (__attribute__((address_space(1))) void*)(g),      \
    (__attribute__((address_space(3))) void*)(s), 16, 0, 0)

#define BARX() asm volatile("s_barrier" ::: "memory")
#define VMW(n) asm volatile("s_waitcnt vmcnt(" #n ")" ::: "memory")

// ---------------------------------------------------------------- conversions
__global__ __launch_bounds__(256)
void cvt_f32_bf16(const float* __restrict__ in, u16t* __restrict__ outp, int n) {
    int i = (blockIdx.x * 256 + threadIdx.x) * 8;
    if (i >= n) return;
    float4 a = *(const float4*)(in + i);
    float4 b = *(const float4*)(in + i + 4);
    union { u16t h[8]; uint4 q; } u;
    u.h[0] = bf16r(a.x); u.h[1] = bf16r(a.y); u.h[2] = bf16r(a.z); u.h[3] = bf16r(a.w);
    u.h[4] = bf16r(b.x); u.h[5] = bf16r(b.y); u.h[6] = bf16r(b.z); u.h[7] = bf16r(b.w);
    *(uint4*)(outp + i) = u.q;
}

// in: (Kd, Nd) f32 row-major -> out: (Nd, Kd) bf16 row-major
__global__ __launch_bounds__(256)
void transpose_w(const float* __restrict__ in, u16t* __restrict__ outp, int Kd, int Nd) {
    __shared__ float tile[32][33];
    const int n0 = blockIdx.x * 32, k0 = blockIdx.y * 32;
    const int tx = threadIdx.x & 31, ty = threadIdx.x >> 5;
    for (int yy = ty; yy < 32; yy += 8)
        tile[yy][tx] = in[(size_t)(k0 + yy) * Nd + n0 + tx];
    __syncthreads();
    for (int yy = ty; yy < 32; yy += 8)
        outp[(size_t)(n0 + yy) * Kd + k0 + tx] = bf16r(tile[tx][yy]);
}

// ---------------------------------------------------------------- GEMM
// C(M,N) f32 = A(M,K)bf16 * Bt(N,K)bf16^T + bias.  128^2 tile, BK=64, dbuf.
// COUNTED-vmcnt pipeline (T4): per K-tile {issue stage(t+1) -> vmcnt(8) -> barrier
// -> compute -> barrier}; loads stay in flight across barriers (raw s_barrier, no
// vmcnt0 drain -- the round-2/4 structures drained every tile via __syncthreads).
// TPB tiles chained per block: next tile's k0-stage hides under the epilogue.
// MODE 0: plain f32 C.  MODE 1: qkv epilogue (q scaled, k+present, v transposed).
template<int MODE, int TPB>
__global__ __launch_bounds__(256, 2)
void gemm_bt(const u16t* __restrict__ A, const u16t* __restrict__ Bt,
             const float* __restrict__ bias, float* __restrict__ C,
             float* __restrict__ pres, u16t* __restrict__ qb,
             u16t* __restrict__ kb, u16t* __restrict__ vtb,
             int N, int K)
{
    __shared__ u16t ldsA[2][128 * 64];
    __shared__ u16t ldsB[2][128 * 64];
    const int tid = threadIdx.x;
    const int w = tid >> 6, l = tid & 63;
    const int wr = w >> 1, wc = w & 1;
    const int lr = l & 15, lq = l >> 4;

    auto stage = [&](int bm, int bn, int k0, int pi) {   // exactly 8 GLDS16/thread
#pragma unroll
        for (int c = 0; c < 4; ++c) {
            const int L = ((w * 64 + l) << 4) + (c << 12);
            const int row = L >> 7;
            const int col = (((L >> 4) & 7) ^ (row & 7)) << 3;  // inverse-swizzled source
            GLDS16(A + (size_t)(bm + row) * K + k0 + col,
                   (char*)ldsA[pi] + (w << 10) + (c << 12));
            GLDS16(Bt + (size_t)(bn + row) * K + k0 + col,
                   (char*)ldsB[pi] + (w << 10) + (c << 12));
        }
    };

    const int nt = K >> 6;

#pragma unroll
    for (int j = 0; j < TPB; ++j) {
        const int idx = blockIdx.x * TPB + j;
        const int bm = (idx & 63) << 7;    // 64 M-tiles, consecutive idx share bn
        const int bn = (idx >> 6) << 7;

        f4 acc[4][4] = {};
        if (j == 0) stage(bm, bn, 0, 0);

        for (int t = 0; t < nt; ++t) {
            if (t + 1 < nt) {
                stage(bm, bn, (t + 1) << 6, (t + 1) & 1);
            } else if (j + 1 < TPB) {
                const int nx = idx + 1;
                stage((nx & 63) << 7, (nx >> 6) << 7, 0, 0);
            }
            if (t + 1 == nt && j + 1 == TPB) { VMW(0); } else { VMW(8); }
            BARX();   // dbuf[t&1] landed; waves aligned
            const char* La = (const char*)ldsA[t & 1];
            const char* Lb = (const char*)ldsB[t & 1];
#pragma unroll
            for (int ks = 0; ks < 2; ++ks) {
                y8 af[4], bfv[4];
#pragma unroll
                for (int m = 0; m < 4; ++m) {
                    const int row = wr * 64 + m * 16 + lr;
                    const int slot = (lq + ks * 4) ^ (row & 7);
                    af[m] = *(const y8*)(La + row * 128 + (slot << 4));
                }
#pragma unroll
                for (int n = 0; n < 4; ++n) {
                    const int row = wc * 64 + n * 16 + lr;
                    const int slot = (lq + ks * 4) ^ (row & 7);
                    bfv[n] = *(const y8*)(Lb + row * 128 + (slot << 4));
                }
#pragma unroll
                for (int m = 0; m < 4; ++m)
#pragma unroll
                    for (int n = 0; n < 4; ++n)
                        acc[m][n] = __builtin_amdgcn_mfma_f32_16x16x32_bf16(af[m], bfv[n], acc[m][n], 0, 0, 0);
            }
            BARX();   // all waves' ds_reads of dbuf[t&1] complete (lgkm'd before MFMA issue)
        }

        if (MODE == 0) {
#pragma unroll
            for (int m = 0; m < 4; ++m) {
                const int rowb = bm + wr * 64 + m * 16 + 4 * lq;
#pragma unroll
                for (int n = 0; n < 4; ++n) {
                    const int col = bn + wc * 64 + n * 16 + lr;
                    const float bv = bias[col];
#pragma unroll
                    for (int r = 0; r < 4; ++r)
                        C[(size_t)(rowb + r) * N + col] = acc[m][n][r] + bv;
                }
            }
        } else {
            const int part = bn >> 10;  // 0=q, 1=k, 2=v (128-col tiles never cross 1024)
#pragma unroll
            for (int m = 0; m < 4; ++m) {
                const int rowb = bm + wr * 64 + m * 16 + 4 * lq;
                const int b0 = rowb >> 11, t0 = rowb & 2047;  // 4 rows never cross batch
#pragma unroll
                for (int n = 0; n < 4; ++n) {
                    const int colg = bn + wc * 64 + n * 16 + lr;
                    const float bv = bias[colg];
                    const int cl = colg & 1023;
                    const int h = cl >> 6, d = cl & 63;
                    float vals[4];
#pragma unroll
                    for (int r = 0; r < 4; ++r) vals[r] = acc[m][n][r] + bv;
                    if (part == 0) {
#pragma unroll
                        for (int r = 0; r < 4; ++r)
                            qb[(((size_t)(b0 * HH + h)) * TT + t0 + r) * 64 + d] =
                                bf16r(vals[r] * QSCALE);
                    } else if (part == 1) {
#pragma unroll
                        for (int r = 0; r < 4; ++r) {
                            kb[(((size_t)(b0 * HH + h)) * TT + t0 + r) * 64 + d] = bf16r(vals[r]);
                            pres[OUT0 + (((size_t)((b0 * 2 + 0) * HH + h)) * TT + t0 + r) * 64 + d] = vals[r];
                        }
                    } else {
#pragma unroll
                        for (int r = 0; r < 4; ++r)
                            pres[OUT0 + (((size_t)((b0 * 2 + 1) * HH + h)) * TT + t0 + r) * 64 + d] = vals[r];
                        uint2 pk;
                        pk.x = cvtpk(vals[0], vals[1]);
                        pk.y = cvtpk(vals[2], vals[3]);
                        *(uint2*)(vtb + ((size_t)(b0 * HH + h) * 64 + d) * TT + t0) = pk;
                    }
                }
            }
        }
        // no barrier needed: next tile's first stage targets a buffer whose reads
        // completed at the compute-end barrier above.
    }
}

// ---------------------------------------------------------------- attention
// Block = (qt, bh): 128 q-rows, 4 waves x 32 rows. KV tile 64, double-buffered.
// SWAPPED operands: S = mfma(K,Q) so softmax state is per-lane (query = lane&15);
// O = mfma(V,P) keeps query = lane&15. Softmax in exp2 domain (scale folded into Q).
// T13 defer-max (THR=8). P routed via per-wave swizzled LDS (b64 packed writes).
__global__ __launch_bounds__(256, 2)
void attn_fwd(const u16t* __restrict__ qg, const u16t* __restrict__ kg,
              const u16t* __restrict__ vtg, u16t* __restrict__ og)
{
    __shared__ u16t sQ[128 * 64];      // 16 KB
    __shared__ u16t sK[2 * 64 * 64];   // 16 KB (double buffer)
    __shared__ u16t sV[2 * 64 * 64];   // 16 KB
    __shared__ u16t sP[4 * 32 * 64];   // 16 KB (per-wave 32x64)
    const int tid = threadIdx.x;
    const int w = tid >> 6, l = tid & 63;
    const int lr = l & 15, lq = l >> 4;
    const int qt = 15 - blockIdx.y;    // long blocks first
    const int bh = blockIdx.x;
    const int b = bh >> 4, h = bh & 15;
    const u16t* qsrc = qg + (size_t)bh * TT * 64;
    const u16t* ksrc = kg + (size_t)bh * TT * 64;
    const u16t* vsrc = vtg + (size_t)bh * 64 * TT;

    auto stageKV = [&](int kt, int pi) {
        const int kv0 = kt << 6;
#pragma unroll
        for (int c = 0; c < 2; ++c) {
            const int L = ((w * 64 + l) << 4) + (c << 12);
            const int row = L >> 7;
            const int col = (((L >> 4) & 7) ^ (row & 7)) << 3;
            GLDS16(ksrc + (kv0 + row) * 64 + col,
                   (char*)sK + (pi << 13) + (w << 10) + (c << 12));
            GLDS16(vsrc + (size_t)row * TT + kv0 + col,
                   (char*)sV + (pi << 13) + (w << 10) + (c << 12));
        }
    };

    // stage Q tile (128 x 64) + KV tile 0
#pragma unroll
    for (int c = 0; c < 4; ++c) {
        const int L = ((w * 64 + l) << 4) + (c << 12);
        const int row = L >> 7;
        const int col = (((L >> 4) & 7) ^ (row & 7)) << 3;
        GLDS16(qsrc + (qt * 128 + row) * 64 + col, (char*)sQ + (w << 10) + (c << 12));
    }
    stageKV(0, 0);
    __syncthreads();

    y8 qf[2][2];
#pragma unroll
    for (int qm = 0; qm < 2; ++qm)
#pragma unroll
        for (int ks = 0; ks < 2; ++ks) {
            const int row = w * 32 + qm * 16 + lr;
            const int slot = (lq + ks * 4) ^ (row & 7);
            qf[qm][ks] = *(const y8*)((const char*)sQ + row * 128 + (slot << 4));
        }

    f4 o[2][4] = {};
    float mrow[2] = {-1e30f, -1e30f};
    float lsum[2] = {0.f, 0.f};

    char* Pw = (char*)sP + (w << 12);  // per-wave 32x64 bf16 region
    const int qmax = qt * 128 + w * 32 + 31;  // wave's last q-row
    const int ktiles = 2 * qt + 2;
    int cur = 0;

    for (int kt = 0; kt < ktiles; ++kt) {
        __syncthreads();  // buf[cur] staged; all waves done reading buf[cur^1]
        if (kt + 1 < ktiles) stageKV(kt + 1, cur ^ 1);
        const int kv0 = kt << 6;
        if (kv0 <= qmax) {  // tile not fully masked for this wave
            const char* Kb = (const char*)sK + (cur << 13);
            const char* Vb = (const char*)sV + (cur << 13);

            // S^T tiles: s[qm][n] = mfma(K,Q): lane holds S[key n*16+4lq+r][query lane&15]
            f4 s[2][4] = {};
            __builtin_amdgcn_s_setprio(1);
#pragma unroll
            for (int ks = 0; ks < 2; ++ks) {
                y8 kf[4];
#pragma unroll
                for (int n = 0; n < 4; ++n) {
                    const int row = n * 16 + lr;
                    const int slot = (lq + ks * 4) ^ (row & 7);
                    kf[n] = *(const y8*)(Kb + row * 128 + (slot << 4));
                }
#pragma unroll
                for (int qm = 0; qm < 2; ++qm)
#pragma unroll
                    for (int n = 0; n < 4; ++n)
                        s[qm][n] = __builtin_amdgcn_mfma_f32_16x16x32_bf16(kf[n], qf[qm][ks], s[qm][n], 0, 0, 0);
            }
            __builtin_amdgcn_s_setprio(0);

#pragma unroll
            for (int qm = 0; qm < 2; ++qm) {
                const int qb0 = qt * 128 + w * 32 + qm * 16;
                if (kv0 + 63 > qb0) {  // tile crosses diagonal for this m-tile
                    const int query = qb0 + lr;
#pragma unroll
                    for (int n = 0; n < 4; ++n)
#pragma unroll
                        for (int r = 0; r < 4; ++r)
                            if (kv0 + n * 16 + 4 * lq + r > query) s[qm][n][r] = -1e30f;
                }

                // per-lane row max (query = lane&15): in-lane tree + 2 shfls
                float mx = -1e30f;
#pragma unroll
                for (int n = 0; n < 4; ++n)
                    mx = fmaxf(mx, fmaxf(fmaxf(s[qm][n][0], s[qm][n][1]),
                                         fmaxf(s[qm][n][2], s[qm][n][3])));
                mx = fmaxf(mx, __shfl_xor(mx, 16));
                mx = fmaxf(mx, __shfl_xor(mx, 32));

                // T13 defer-max: rescale only when max grows past THR=8 (exp2 domain)
                if (!__all(mx <= mrow[qm] + 8.f)) {
                    const float newm = fmaxf(mrow[qm], mx);
                    const float corr = exp2f(mrow[qm] - newm);
                    mrow[qm] = newm;
                    lsum[qm] *= corr;
#pragma unroll
                    for (int n = 0; n < 4; ++n) o[qm][n] *= corr;
                }

                float rs = 0.f;
#pragma unroll
                for (int n = 0; n < 4; ++n)
#pragma unroll
                    for (int r = 0; r < 4; ++r) {
                        const float p = exp2f(s[qm][n][r] - mrow[qm]);
                        s[qm][n][r] = p;
                        rs += p;
                    }
                lsum[qm] += rs;

                // P -> per-wave LDS: keys contiguous over r -> packed b64 writes
                const int prow = qm * 16 + lr;
                const int rbase = prow * 128 + ((lq & 1) << 3);
#pragma unroll
                for (int n = 0; n < 4; ++n) {
                    uint2 pk;
                    pk.x = cvtpk(s[qm][n][0], s[qm][n][1]);
                    pk.y = cvtpk(s[qm][n][2], s[qm][n][3]);
                    const int sIdx = 2 * n + (lq >> 1);
                    *(uint2*)(Pw + rbase + ((sIdx ^ (prow & 7)) << 4)) = pk;
                }
            }

            // O += V^T x P (swapped): lane holds O[d=n*16+4lq+r][query lane&15]
            __builtin_amdgcn_s_setprio(1);
#pragma unroll
            for (int ks = 0; ks < 2; ++ks) {
                y8 vf[4], pf[2];
#pragma unroll
                for (int n = 0; n < 4; ++n) {
                    const int row = n * 16 + lr;
                    const int slot = (lq + ks * 4) ^ (row & 7);
                    vf[n] = *(const y8*)(Vb + row * 128 + (slot << 4));
                }
#pragma unroll
                for (int qm = 0; qm < 2; ++qm) {
                    const int row = qm * 16 + lr;
                    const int slot = (lq + ks * 4) ^ (row & 7);
                    pf[qm] = *(const y8*)(Pw + row * 128 + (slot << 4));
                }
#pragma unroll
                for (int qm = 0; qm < 2; ++qm)
#pragma unroll
                    for (int n = 0; n < 4; ++n)
                        o[qm][n] = __builtin_amdgcn_mfma_f32_16x16x32_bf16(vf[n], pf[qm], o[qm][n], 0, 0, 0);
            }
            __builtin_amdgcn_s_setprio(0);
        }
        cur ^= 1;
    }

    // epilogue: lsum reduce (2 shfls), normalize, packed bf16 store
#pragma unroll
    for (int qm = 0; qm < 2; ++qm) {
        float t = lsum[qm];
        t += __shfl_xor(t, 16);
        t += __shfl_xor(t, 32);
        const float inv = 1.0f / t;
        const int trow = qt * 128 + w * 32 + qm * 16 + lr;
#pragma unroll
        for (int n = 0; n < 4; ++n) {
            uint2 pk;
            pk.x = cvtpk(o[qm][n][0] * inv, o[qm][n][1] * inv);
            pk.y = cvtpk(o[qm][n][2] * inv, o[qm][n][3] * inv);
            *(uint2*)(og + ((size_t)(b * TT + trow)) * DD + h * 64 + n * 16 + 4 * lq) = pk;
        }
    }
}

// ---------------------------------------------------------------- launch
extern "C" void kernel_launch(void* const* d_in, const int* in_sizes, int n_in,
                              void* d_out, int out_size, void* d_ws, size_t ws_size,
                              hipStream_t stream) {
    const float* x      = (const float*)d_in[0];
    const float* w_attn = (const float*)d_in[1];
    const float* b_attn = (const float*)d_in[2];
    const float* w_proj = (const float*)d_in[3];
    const float* b_proj = (const float*)d_in[4];
    float* outp = (float*)d_out;
    char* ws = (char*)d_ws;

    // workspace layout (bytes)
    u16t* xb  = (u16t*)(ws + 0);          // 8192x1024 bf16 (x, later reused as attn_out)
    u16t* wta = (u16t*)(ws + 16777216);   // 3072x1024 bf16 (w_attn^T)
    u16t* wtp = (u16t*)(ws + 23068672);   // 1024x1024 bf16 (w_proj^T)
    u16t* qb  = (u16t*)(ws + 25165824);   // (B,H,T,64) bf16, pre-scaled by QSCALE
    u16t* kb  = (u16t*)(ws + 41943040);   // (B,H,T,64) bf16
    u16t* vtb = (u16t*)(ws + 58720256);   // (B,H,64,T) bf16 (written transposed by GEMM)
    if (ws_size < 75497472) return;       // loud failure rather than OOB writes

    cvt_f32_bf16<<<4096, 256, 0, stream>>>(x, xb, 8388608);
    transpose_w<<<dim3(96, 32), 256, 0, stream>>>(w_attn, wta, 1024, 3072);
    transpose_w<<<dim3(32, 32), 256, 0, stream>>>(w_proj, wtp, 1024, 1024);

    // qkv: 64x24 = 1536 tiles, 3 per block -> 512 blocks (2/CU, one exact round)
    gemm_bt<1, 3><<<512, 256, 0, stream>>>(xb, wta, b_attn, nullptr, outp,
                                           qb, kb, vtb, 3072, 1024);
    attn_fwd<<<dim3(64, 16), 256, 0, stream>>>(qb, kb, vtb, xb /* reuse as attn_out */);
    // proj: 64x8 = 512 tiles, 1 per block -> 512 blocks
    gemm_bt<0, 1><<<512, 256, 0, stream>>>(xb, wtp, b_proj, outp,
                                           nullptr, nullptr, nullptr, nullptr,
                                           1024, 1024);
}